// Round 1
// baseline (313.777 us; speedup 1.0000x reference)
//
#include <hip/hip_runtime.h>
#include <hip/hip_bf16.h>

// Attention_4363686773373: sigmoid attention block, all-bf16 MFMA pipeline.
// B=4 T=2048 D=768 H=12 HD=64.  Output fp32.
// R12: attn 2-tile software pipeline (T15): QK(i) MFMAs issue first, then
//  sigmoid+PV of tile i-1 run in their shadow (independent regs). K/V dbuf
//  schedules skewed by one tile (commit K(i+1) & V(i) during iter i) so LDS
//  stays 48KB -> 3 blocks/CU. s_setprio(1) around both MFMA clusters (T5).
// GEMMs: distance-2 named-register prefetch, launch_bounds(256,2) (R10).

typedef __bf16 bf16_t;
typedef __bf16 bf16x8 __attribute__((ext_vector_type(8)));
typedef __bf16 bf16x4 __attribute__((ext_vector_type(4)));
typedef __bf16 bf16x2 __attribute__((ext_vector_type(2)));
typedef float floatx4 __attribute__((ext_vector_type(4)));

#define MFMA16x16x32(a, b, c) __builtin_amdgcn_mfma_f32_16x16x32_bf16((a), (b), (c), 0, 0, 0)

static constexpr float kEPS  = 1e-4f;
static constexpr float kGAIN = 1.8402f;
static constexpr float kC    = -0.18033688011112042f;   // -0.125 * log2(e)

#if __has_builtin(__builtin_amdgcn_cvt_pk_bf16_f32)
__device__ __forceinline__ bf16x2 pk_bf16(float a, float b) {
    return __builtin_amdgcn_cvt_pk_bf16_f32(a, b);
}
#else
__device__ __forceinline__ bf16x2 pk_bf16(float a, float b) {
    bf16x2 r; r[0] = (bf16_t)a; r[1] = (bf16_t)b; return r;
}
#endif

// ---------------------------------------------------------------------------
// 1) merged preprocessing:
//    blocks [0,3072): row-normalize [qkv_w ; out_w] rows -> bf16
//    blocks [3072,11264): x -> bf16 + per-token magnitude ||x||/sqrt(D)
// ---------------------------------------------------------------------------
__global__ __launch_bounds__(256) void prep_kernel(const float* __restrict__ x,
                                                   const float* __restrict__ qkv_w,
                                                   const float* __restrict__ out_w,
                                                   bf16_t* __restrict__ wn_all,
                                                   bf16_t* __restrict__ xb,
                                                   float* __restrict__ mag) {
    __shared__ float red[4];
    int b = blockIdx.x;
    if (b < 3072) {
        const float* wr = (b < 2304) ? qkv_w + (size_t)b * 768
                                     : out_w + (size_t)(b - 2304) * 768;
        float ss = 0.f;
        for (int c = threadIdx.x; c < 768; c += 256) { float v = wr[c]; ss += v * v; }
        for (int m = 32; m; m >>= 1) ss += __shfl_xor(ss, m, 64);
        if ((threadIdx.x & 63) == 0) red[threadIdx.x >> 6] = ss;
        __syncthreads();
        float inv = 1.0f / (sqrtf(red[0] + red[1] + red[2] + red[3]) + kEPS);
        bf16_t* wo = wn_all + (size_t)b * 768;
        for (int c = threadIdx.x; c < 768; c += 256) wo[c] = (bf16_t)(wr[c] * inv);
    } else {
        int tok = b - 3072;               // 0..8191
        const float* xr = x + (size_t)tok * 768;
        float ss = 0.f;
        for (int c = threadIdx.x; c < 768; c += 256) { float v = xr[c]; ss += v * v; }
        for (int m = 32; m; m >>= 1) ss += __shfl_xor(ss, m, 64);
        if ((threadIdx.x & 63) == 0) red[threadIdx.x >> 6] = ss;
        __syncthreads();
        float tot = red[0] + red[1] + red[2] + red[3];
        if (threadIdx.x == 0) mag[tok] = sqrtf(tot) * 0.036084391824352f;  // 1/sqrt(768)
        bf16_t* xo = xb + (size_t)tok * 768;
        for (int c = threadIdx.x; c < 768; c += 256) xo[c] = (bf16_t)xr[c];
    }
}

// ---------------------------------------------------------------------------
// 3) GEMM1: qkv = xb(8192x768) @ wn^T(2304x768).  128x128 tile, BK=32,
//    distance-2 register prefetch with NAMED registers. Lane-order LDS.
//    Epilogue: q/k per-head normalize (q also *kC) -> qkvh; v (p==2)
//    transposed via LDS to vT (pi-permuted columns).
// ---------------------------------------------------------------------------
__global__ __launch_bounds__(256, 2) void gemm_qkv_kernel(const bf16_t* __restrict__ A,
                                                          const bf16_t* __restrict__ Bw,
                                                          bf16_t* __restrict__ qkvh,
                                                          bf16_t* __restrict__ vT) {
    __shared__ __align__(16) bf16_t sm[8704];   // As 4096 | Bs 4096; reused 64x136 for v-transpose
    bf16_t* As = sm;
    bf16_t* Bs = sm + 4096;

    const int m0 = blockIdx.x * 128;
    const int n0 = blockIdx.y * 128;
    const int tid = threadIdx.x;
    const int wave = tid >> 6, lane = tid & 63;
    const int quad = lane >> 4, l16 = lane & 15;
    const int wr = (wave >> 1) * 64, wc = (wave & 1) * 64;
    const int srow = lane & 15, schunk = lane >> 4;   // staging lane map

    floatx4 acc[4][4];
    for (int i = 0; i < 4; i++)
        for (int j = 0; j < 4; j++) acc[i][j] = (floatx4){0.f, 0.f, 0.f, 0.f};

    const bf16_t* aptr0 = A  + (size_t)(m0 + wave * 32 + srow) * 768 + schunk * 8;
    const bf16_t* bptr0 = Bw + (size_t)(n0 + wave * 32 + srow) * 768 + schunk * 8;
    const int abase = wave * 1024;                    // per-wave region: 2 x 512

    // two prefetch sets, NAMED registers (arrays spilled in R9)
    uint4 aA0, aA1, bA0, bA1, aB0, aB1, bB0, bB1;

    aA0 = *(const uint4*)(aptr0 + 0);
    aA1 = *(const uint4*)(aptr0 + 0 + 16 * 768);
    bA0 = *(const uint4*)(bptr0 + 0);
    bA1 = *(const uint4*)(bptr0 + 0 + 16 * 768);
    aB0 = *(const uint4*)(aptr0 + 32);
    aB1 = *(const uint4*)(aptr0 + 32 + 16 * 768);
    bB0 = *(const uint4*)(bptr0 + 32);
    bB1 = *(const uint4*)(bptr0 + 32 + 16 * 768);

    auto compute = [&]() {
        bf16x8 af[4], bfr[4];
#pragma unroll
        for (int i = 0; i < 4; i++)
            af[i] = *(const bf16x8*)&As[((wr >> 4) + i) * 512 + quad * 128 + l16 * 8];
#pragma unroll
        for (int j = 0; j < 4; j++)
            bfr[j] = *(const bf16x8*)&Bs[((wc >> 4) + j) * 512 + quad * 128 + l16 * 8];
#pragma unroll
        for (int i = 0; i < 4; i++)
#pragma unroll
            for (int j = 0; j < 4; j++) acc[i][j] = MFMA16x16x32(af[i], bfr[j], acc[i][j]);
    };

    for (int u = 0; u < 12; ++u) {
        // even iteration: consume set A, refill A for k=(2u+2)*32
        __syncthreads();
        *(uint4*)&As[abase + lane * 8]       = aA0;
        *(uint4*)&As[abase + 512 + lane * 8] = aA1;
        *(uint4*)&Bs[abase + lane * 8]       = bA0;
        *(uint4*)&Bs[abase + 512 + lane * 8] = bA1;
        if (u < 11) {
            int k0 = (2 * u + 2) * 32;
            aA0 = *(const uint4*)(aptr0 + k0);
            aA1 = *(const uint4*)(aptr0 + k0 + 16 * 768);
            bA0 = *(const uint4*)(bptr0 + k0);
            bA1 = *(const uint4*)(bptr0 + k0 + 16 * 768);
        }
        __syncthreads();
        compute();

        // odd iteration: consume set B, refill B for k=(2u+3)*32
        __syncthreads();
        *(uint4*)&As[abase + lane * 8]       = aB0;
        *(uint4*)&As[abase + 512 + lane * 8] = aB1;
        *(uint4*)&Bs[abase + lane * 8]       = bB0;
        *(uint4*)&Bs[abase + 512 + lane * 8] = bB1;
        if (u < 11) {
            int k0 = (2 * u + 3) * 32;
            aB0 = *(const uint4*)(aptr0 + k0);
            aB1 = *(const uint4*)(aptr0 + k0 + 16 * 768);
            bB0 = *(const uint4*)(bptr0 + k0);
            bB1 = *(const uint4*)(bptr0 + k0 + 16 * 768);
        }
        __syncthreads();
        compute();
    }

    const int p = n0 / 768;        // block-uniform (768 % 128 == 0)
    const int bat = m0 >> 11, t0 = m0 & 2047;

    if (p < 2) {
        // ---- q/k: fused per-head normalize, scatter to qkvh ----
        const int h = ((n0 + wc) - p * 768) >> 6;
        const float base = (p == 0) ? kC * 8.0f : 8.0f;
        for (int i = 0; i < 4; i++)
            for (int r = 0; r < 4; r++) {
                float vals[4], ss = 0.f;
                for (int j = 0; j < 4; j++) { float v = acc[i][j][r]; vals[j] = v; ss += v * v; }
                ss += __shfl_xor(ss, 1, 64);
                ss += __shfl_xor(ss, 2, 64);
                ss += __shfl_xor(ss, 4, 64);
                ss += __shfl_xor(ss, 8, 64);
                float scale = base / (sqrtf(ss) + kEPS);
                int m = m0 + wr + i * 16 + quad * 4 + r;
                int t = m & 2047;
                bf16_t* dst = qkvh + ((((size_t)p * 4 + bat) * 12 + h) * 2048 + t) * 64;
                for (int j = 0; j < 4; j++) dst[j * 16 + l16] = (bf16_t)(vals[j] * scale);
            }
    } else {
        // ---- v: transpose via LDS, write vT[(bh)*64+d][t] pi-permuted ----
        __syncthreads();                         // everyone done with As/Bs
        const int h0 = (n0 - 1536) >> 6;         // block head base (2 heads/block)
        for (int hh = 0; hh < 2; hh++) {
            if ((wc >> 6) == hh) {
                for (int i = 0; i < 4; i++)
                    for (int r = 0; r < 4; r++) {
                        int tl = wr + i * 16 + quad * 4 + r;
                        for (int j = 0; j < 4; j++)
                            sm[(j * 16 + l16) * 136 + tl] = (bf16_t)acc[i][j][r];
                    }
            }
            __syncthreads();
            bf16_t* dst = vT + ((size_t)(bat * 12 + h0 + hh) * 64) * 2048 + t0;
            for (int u = tid; u < 1024; u += 256) {
                int d = u >> 4, c = u & 15;
                bf16_t tmp[8];
#pragma unroll
                for (int q = 0; q < 8; q++) {
                    int sp = c * 8 + q;                      // out position 0..127
                    int q6 = sp & 63;
                    int tl = (sp & 64) + ((q6 & 3) << 4) + (q6 >> 2);   // pi_inv
                    tmp[q] = sm[d * 136 + tl];
                }
                *(uint4*)&dst[(size_t)d * 2048 + c * 8] = *(uint4*)tmp;
            }
            __syncthreads();
        }
    }
}

// ---------------------------------------------------------------------------
// 6) sigmoid attention, fused per-head output normalize + mag rescale.
//    grid (48, 16): x = head (XCD-affine), y = q-tile. 512 thr = 8 waves x
//    16 q-rows. s-tile 64, one barrier per s-tile.
//    R12: 2-tile pipeline. Iter i: QK(i) MFMAs issue first; sigmoid+PV of
//    tile i-1 execute in their shadow. K commit leads V commit by one tile:
//      iter i reads  K(i)   [Ksh[i&1]]   and V(i-1) [Vsh[(i-1)&1]]
//      iter i writes K(i+1) [Ksh[(i+1)&1]] and V(i) [Vsh[i&1]]
//    -> no buffer is read and written in the same inter-barrier interval.
// ---------------------------------------------------------------------------
__global__ __launch_bounds__(512, 6) void attn_kernel(const bf16_t* __restrict__ qkvh,
                                                      const bf16_t* __restrict__ vT,
                                                      const float* __restrict__ mag,
                                                      bf16_t* __restrict__ y) {
    __shared__ bf16_t QP[128 * 64];          // Q tile, then reused as Ps (wave-private rows)
    __shared__ bf16_t Ksh[2][64 * 64];
    __shared__ bf16_t Vsh[2][64 * 64];       // pi-ordered V

    const int bh = blockIdx.x, bat = bh / 12, h = bh % 12;
    const int m0 = blockIdx.y * 128;
    const bf16_t* qbase = qkvh + (((size_t)bat * 12 + h) * 2048) * 64;            // p=0
    const bf16_t* kbase = qkvh + (((size_t)(4 + bat) * 12 + h) * 2048) * 64;      // p=1
    const bf16_t* vbase = vT + ((size_t)bh * 64) * 2048;

    const int tid = threadIdx.x, wave = tid >> 6, lane = tid & 63;
    const int quad = lane >> 4, l16 = lane & 15;

    // ---- stage Q (swizzled): 1024 uint4 over 512 threads ----
    for (int s = tid; s < 1024; s += 512) {
        int r = s >> 3, blk = s & 7;
        *(uint4*)&QP[r * 64 + ((blk ^ (r & 7)) * 8)] =
            *(const uint4*)&qbase[(size_t)(m0 + r) * 64 + blk * 8];
    }

    // ---- K/V prefetch (1 uint4 of each per thread, independent schedules) ----
    uint4 kr, vr;
    const int slr = tid >> 3, slb = tid & 7;
    const int sw = ((slb ^ (slr & 7)) * 8);
    auto issueK  = [&](int s0) { kr = *(const uint4*)&kbase[(size_t)(s0 + slr) * 64 + slb * 8]; };
    auto issueV  = [&](int s0) { vr = *(const uint4*)&vbase[(size_t)slr * 2048 + s0 + slb * 8]; };
    auto commitK = [&](int buf) { *(uint4*)&Ksh[buf][slr * 64 + sw] = kr; };
    auto commitV = [&](int buf) { *(uint4*)&Vsh[buf][slr * 64 + sw] = vr; };

    issueK(0);
    __syncthreads();   // Q staged

    // ---- Q fragments -> registers (wave-private rows; QP freed for Ps) ----
    const int qrow = wave * 16 + l16;
    bf16x8 qf0 = *(const bf16x8*)&QP[qrow * 64 + ((quad ^ (l16 & 7)) * 8)];
    bf16x8 qf1 = *(const bf16x8*)&QP[qrow * 64 + (((4 + quad) ^ (l16 & 7)) * 8)];

    commitK(0);        // K(0)
    issueK(64);        // K(1)
    issueV(0);         // V(0)
    __syncthreads();   // Ksh[0] visible; all qf reads done before Ps writes

    const floatx4 fz = (floatx4){0.f, 0.f, 0.f, 0.f};   // loop-invariant zero C

    floatx4 o[4];
#pragma unroll
    for (int j = 0; j < 4; j++) o[j] = fz;

    floatx4 sA[4], sB[4];

    // ---- S = Q.K^T into sc (16 q-rows x 64 s per wave) ----
    auto qk = [&](floatx4* sc, const bf16_t* Ks) {
        __builtin_amdgcn_s_setprio(1);
#pragma unroll
        for (int j = 0; j < 4; j++) {
            int row = j * 16 + l16;
            bf16x8 b0 = *(const bf16x8*)&Ks[row * 64 + ((quad ^ (l16 & 7)) * 8)];
            bf16x8 b1 = *(const bf16x8*)&Ks[row * 64 + (((4 + quad) ^ (l16 & 7)) * 8)];
            sc[j] = MFMA16x16x32(qf0, b0, fz);
            sc[j] = MFMA16x16x32(qf1, b1, sc[j]);
        }
        __builtin_amdgcn_s_setprio(0);
    };

    // ---- sigmoid(prev S) -> Ps, then O += P.V ----
    auto finish = [&](const floatx4* sc, const bf16_t* Vt) {
#pragma unroll
        for (int r = 0; r < 4; r++) {
            int row = wave * 16 + quad * 4 + r;
            float s0 = __builtin_amdgcn_rcpf(1.0f + __builtin_amdgcn_exp2f(sc[0][r]));
            float s1 = __builtin_amdgcn_rcpf(1.0f + __builtin_amdgcn_exp2f(sc[1][r]));
            float s2 = __builtin_amdgcn_rcpf(1.0f + __builtin_amdgcn_exp2f(sc[2][r]));
            float s3 = __builtin_amdgcn_rcpf(1.0f + __builtin_amdgcn_exp2f(sc[3][r]));
            bf16x2 lo = pk_bf16(s0, s1);
            bf16x2 hi = pk_bf16(s2, s3);
            bf16x4 pk = __builtin_shufflevector(lo, hi, 0, 1, 2, 3);
            *(bf16x4*)&QP[row * 64 + (((l16 >> 1) ^ (row & 7)) * 8) + (l16 & 1) * 4] = pk;
        }
        const int prow = wave * 16 + l16;
        bf16x8 af0 = *(const bf16x8*)&QP[prow * 64 + ((quad ^ (l16 & 7)) * 8)];
        bf16x8 af1 = *(const bf16x8*)&QP[prow * 64 + (((4 + quad) ^ (l16 & 7)) * 8)];
        __builtin_amdgcn_s_setprio(1);
#pragma unroll
        for (int j = 0; j < 4; j++) {
            int row = j * 16 + l16;
            bf16x8 b0 = *(const bf16x8*)&Vt[row * 64 + ((quad ^ (l16 & 7)) * 8)];
            bf16x8 b1 = *(const bf16x8*)&Vt[row * 64 + (((4 + quad) ^ (l16 & 7)) * 8)];
            o[j] = MFMA16x16x32(af0, b0, o[j]);
            o[j] = MFMA16x16x32(af1, b1, o[j]);
        }
        __builtin_amdgcn_s_setprio(0);
    };

    // ---- pipeline prologue: compute S(0); commit K(1), V(0); load K(2), V(1)
    qk(sA, Ksh[0]);
    commitK(1);
    commitV(0);
    issueK(128);
    issueV(64);
    __syncthreads();   // K(1), V(0) visible

    // ---- steady state: pairs (1,2)..(29,30). Invariant at top of iter i:
    //      K(i),V(i-1) visible; kr=K(i+1), vr=V(i); prev S(i-1) resident.
    for (int i = 1; i < 31; i += 2) {
        // iter i (odd): cur=sB, prev=sA
        qk(sB, Ksh[1]);                 // K(i) lives in Ksh[1]
        commitK(0);                     // K(i+1) -> Ksh[0]
        commitV(1);                     // V(i)   -> Vsh[1]
        issueK((i + 2) * 64);           // K(i+2)  (i<=29 -> tile <=31, valid)
        issueV((i + 1) * 64);           // V(i+1)
        finish(sA, Vsh[0]);             // sigmoid S(i-1), PV with V(i-1)
        __syncthreads();

        // iter i+1 (even): cur=sA, prev=sB
        qk(sA, Ksh[0]);
        commitK(1);                     // K(i+2) -> Ksh[1]  (i+2 <= 31, valid)
        commitV(0);                     // V(i+1) -> Vsh[0]
        if (i < 29) issueK((i + 3) * 64);
        issueV((i + 2) * 64);           // V(i+2)  (i+2 <= 31, valid)
        finish(sB, Vsh[1]);
        __syncthreads();
    }

    // ---- iter 31: last QK; commit V(31); finish S(30)
    qk(sB, Ksh[1]);                     // K(31) in Ksh[1]
    commitV(1);                         // V(31) -> Vsh[1]
    finish(sA, Vsh[0]);                 // S(30) with V(30)
    __syncthreads();                    // V(31) visible

    // ---- drain: finish S(31)
    finish(sB, Vsh[1]);

    // ---- epilogue: out = mag * 8 * (kGAIN/sqrt(T)) * o / (||...|| + eps) ----
    const float kfac = kGAIN * 0.02209708691207961f;  // 1.8402/sqrt(2048)
#pragma unroll
    for (int r = 0; r < 4; r++) {
        int t = m0 + wave * 16 + quad * 4 + r;
        float vals[4];
        float ss = 0.f;
#pragma unroll
        for (int j = 0; j < 4; j++) {
            float v = o[j][r] * kfac;
            vals[j] = v;
            ss += v * v;
        }
        for (int msk = 1; msk < 16; msk <<= 1) ss += __shfl_xor(ss, msk, 64);
        float mg = mag[bat * 2048 + t];
        float sc = mg * 8.0f / (sqrtf(ss) + kEPS);
#pragma unroll
        for (int j = 0; j < 4; j++) {
            int d = j * 16 + l16;
            y[((size_t)(bat * 2048 + t)) * 768 + h * 64 + d] = (bf16_t)(vals[j] * sc);
        }
    }
}

// ---------------------------------------------------------------------------
// 7) GEMM2: out = y(8192x768) @ ow^T(768x768) -> fp32, BK=32, distance-2
//    (named prefetch registers, launch_bounds(256,2))
// ---------------------------------------------------------------------------
__global__ __launch_bounds__(256, 2) void gemm_out_kernel(const bf16_t* __restrict__ A,
                                                          const bf16_t* __restrict__ Bw,
                                                          float* __restrict__ out) {
    __shared__ __align__(16) bf16_t sm[8192];
    bf16_t* As = sm;
    bf16_t* Bs = sm + 4096;

    const int m0 = blockIdx.x * 128;
    const int n0 = blockIdx.y * 128;
    const int tid = threadIdx.x;
    const int wave = tid >> 6, lane = tid & 63;
    const int quad = lane >> 4, l16 = lane & 15;
    const int wr = (wave >> 1) * 64, wc = (wave & 1) * 64;
    const int srow = lane & 15, schunk = lane >> 4;

    floatx4 acc[4][4];
    for (int i = 0; i < 4; i++)
        for (int j = 0; j < 4; j++) acc[i][j] = (floatx4){0.f, 0.f, 0.f, 0.f};

    const bf16_t* aptr0 = A  + (size_t)(m0 + wave * 32 + srow) * 768 + schunk * 8;
    const bf16_t* bptr0 = Bw + (size_t)(n0 + wave * 32 + srow) * 768 + schunk * 8;
    const int abase = wave * 1024;

    uint4 aA0, aA1, bA0, bA1, aB0, aB1, bB0, bB1;

    aA0 = *(const uint4*)(aptr0 + 0);
    aA1 = *(const uint4*)(aptr0 + 0 + 16 * 768);
    bA0 = *(const uint4*)(bptr0 + 0);
    bA1 = *(const uint4*)(bptr0 + 0 + 16 * 768);
    aB0 = *(const uint4*)(aptr0 + 32);
    aB1 = *(const uint4*)(aptr0 + 32 + 16 * 768);
    bB0 = *(const uint4*)(bptr0 + 32);
    bB1 = *(const uint4*)(bptr0 + 32 + 16 * 768);

    auto compute = [&]() {
        bf16x8 af[4], bfr[4];
#pragma unroll
        for (int i = 0; i < 4; i++)
            af[i] = *(const bf16x8*)&As[((wr >> 4) + i) * 512 + quad * 128 + l16 * 8];
#pragma unroll
        for (int j = 0; j < 4; j++)
            bfr[j] = *(const bf16x8*)&Bs[((wc >> 4) + j) * 512 + quad * 128 + l16 * 8];
#pragma unroll
        for (int i = 0; i < 4; i++)
#pragma unroll
            for (int j = 0; j < 4; j++) acc[i][j] = MFMA16x16x32(af[i], bfr[j], acc[i][j]);
    };

    for (int u = 0; u < 12; ++u) {
        __syncthreads();
        *(uint4*)&As[abase + lane * 8]       = aA0;
        *(uint4*)&As[abase + 512 + lane * 8] = aA1;
        *(uint4*)&Bs[abase + lane * 8]       = bA0;
        *(uint4*)&Bs[abase + 512 + lane * 8] = bA1;
        if (u < 11) {
            int k0 = (2 * u + 2) * 32;
            aA0 = *(const uint4*)(aptr0 + k0);
            aA1 = *(const uint4*)(aptr0 + k0 + 16 * 768);
            bA0 = *(const uint4*)(bptr0 + k0);
            bA1 = *(const uint4*)(bptr0 + k0 + 16 * 768);
        }
        __syncthreads();
        compute();

        __syncthreads();
        *(uint4*)&As[abase + lane * 8]       = aB0;
        *(uint4*)&As[abase + 512 + lane * 8] = aB1;
        *(uint4*)&Bs[abase + lane * 8]       = bB0;
        *(uint4*)&Bs[abase + 512 + lane * 8] = bB1;
        if (u < 11) {
            int k0 = (2 * u + 3) * 32;
            aB0 = *(const uint4*)(aptr0 + k0);
            aB1 = *(const uint4*)(aptr0 + k0 + 16 * 768);
            bB0 = *(const uint4*)(bptr0 + k0);
            bB1 = *(const uint4*)(bptr0 + k0 + 16 * 768);
        }
        __syncthreads();
        compute();
    }

    for (int i = 0; i < 4; i++)
        for (int j = 0; j < 4; j++) {
            int n = n0 + wc + j * 16 + l16;
            for (int r = 0; r < 4; r++) {
                int m = m0 + wr + i * 16 + quad * 4 + r;
                out[(size_t)m * 768 + n] = acc[i][j][r];
            }
        }
}

// ---------------------------------------------------------------------------
extern "C" void kernel_launch(void* const* d_in, const int* in_sizes, int n_in,
                              void* d_out, int out_size, void* d_ws, size_t ws_size,
                              hipStream_t stream) {
    const float* x     = (const float*)d_in[0];   // (4,2048,768)
    const float* qkv_w = (const float*)d_in[1];   // (2304,768)
    const float* out_w = (const float*)d_in[2];   // (768,768)
    float* out = (float*)d_out;

    char* ws = (char*)d_ws;
    bf16_t* wn_all = (bf16_t*)(ws + 0);          //  4,718,592  (3072x768 bf16: qkv_w rows then out_w rows)
    bf16_t* xb     = (bf16_t*)(ws + 4718592);    // 12,582,912  (8192x768 bf16)
    float*  mag    = (float*) (ws + 17301504);   //     32,768  (8192 fp32)
    bf16_t* qkvh   = (bf16_t*)(ws + 17334272);   // 25,165,824  (2x4x12x2048x64 bf16: q,k)
    bf16_t* vT     = (bf16_t*)(ws + 42500096);   // 12,582,912  (48x64x2048 bf16, pi-permuted cols)
    bf16_t* y      = (bf16_t*)(ws + 55083008);   // 12,582,912  (8192x768 bf16)
    // total 67,665,920 bytes

    bf16_t* ow = wn_all + (size_t)2304 * 768;

    prep_kernel<<<11264, 256, 0, stream>>>(x, qkv_w, out_w, wn_all, xb, mag);
    gemm_qkv_kernel<<<dim3(64, 18), 256, 0, stream>>>(xb, wn_all, qkvh, vT);
    attn_kernel<<<dim3(48, 16), 512, 0, stream>>>(qkvh, vT, mag, y);
    gemm_out_kernel<<<dim3(64, 6), 256, 0, stream>>>(y, ow, out);
}

// Round 2
// 239.155 us; speedup vs baseline: 1.3120x; 1.3120x over previous
//
#include <hip/hip_runtime.h>
#include <hip/hip_bf16.h>

// Attention_4363686773373: sigmoid attention block, all-bf16 MFMA pipeline.
// B=4 T=2048 D=768 H=12 HD=64.  Output fp32.
// R13: R12's 2-tile pipeline with the scratch-spill fixed:
//  - S-tile accumulators are NAMED floatx4 vars (sA0..3 / sB0..3), phases are
//    macros referencing them directly (no pointer params -> no SROA defeat).
//  - launch_bounds(512,4): reg cap 128 (R12's (512,6) cap 85 forced spill).
// Schedule (unchanged, correctness-verified in R12): iter i computes QK(i)
//  first, then sigmoid+PV of tile i-1 in the MFMA shadow; K commit leads V
//  commit by one tile; LDS 48KB.
// GEMMs: distance-2 named-register prefetch, launch_bounds(256,2) (R10).

typedef __bf16 bf16_t;
typedef __bf16 bf16x8 __attribute__((ext_vector_type(8)));
typedef __bf16 bf16x4 __attribute__((ext_vector_type(4)));
typedef __bf16 bf16x2 __attribute__((ext_vector_type(2)));
typedef float floatx4 __attribute__((ext_vector_type(4)));

#define MFMA16x16x32(a, b, c) __builtin_amdgcn_mfma_f32_16x16x32_bf16((a), (b), (c), 0, 0, 0)

static constexpr float kEPS  = 1e-4f;
static constexpr float kGAIN = 1.8402f;
static constexpr float kC    = -0.18033688011112042f;   // -0.125 * log2(e)

#if __has_builtin(__builtin_amdgcn_cvt_pk_bf16_f32)
__device__ __forceinline__ bf16x2 pk_bf16(float a, float b) {
    return __builtin_amdgcn_cvt_pk_bf16_f32(a, b);
}
#else
__device__ __forceinline__ bf16x2 pk_bf16(float a, float b) {
    bf16x2 r; r[0] = (bf16_t)a; r[1] = (bf16_t)b; return r;
}
#endif

// ---------------------------------------------------------------------------
// 1) merged preprocessing:
//    blocks [0,3072): row-normalize [qkv_w ; out_w] rows -> bf16
//    blocks [3072,11264): x -> bf16 + per-token magnitude ||x||/sqrt(D)
// ---------------------------------------------------------------------------
__global__ __launch_bounds__(256) void prep_kernel(const float* __restrict__ x,
                                                   const float* __restrict__ qkv_w,
                                                   const float* __restrict__ out_w,
                                                   bf16_t* __restrict__ wn_all,
                                                   bf16_t* __restrict__ xb,
                                                   float* __restrict__ mag) {
    __shared__ float red[4];
    int b = blockIdx.x;
    if (b < 3072) {
        const float* wr = (b < 2304) ? qkv_w + (size_t)b * 768
                                     : out_w + (size_t)(b - 2304) * 768;
        float ss = 0.f;
        for (int c = threadIdx.x; c < 768; c += 256) { float v = wr[c]; ss += v * v; }
        for (int m = 32; m; m >>= 1) ss += __shfl_xor(ss, m, 64);
        if ((threadIdx.x & 63) == 0) red[threadIdx.x >> 6] = ss;
        __syncthreads();
        float inv = 1.0f / (sqrtf(red[0] + red[1] + red[2] + red[3]) + kEPS);
        bf16_t* wo = wn_all + (size_t)b * 768;
        for (int c = threadIdx.x; c < 768; c += 256) wo[c] = (bf16_t)(wr[c] * inv);
    } else {
        int tok = b - 3072;               // 0..8191
        const float* xr = x + (size_t)tok * 768;
        float ss = 0.f;
        for (int c = threadIdx.x; c < 768; c += 256) { float v = xr[c]; ss += v * v; }
        for (int m = 32; m; m >>= 1) ss += __shfl_xor(ss, m, 64);
        if ((threadIdx.x & 63) == 0) red[threadIdx.x >> 6] = ss;
        __syncthreads();
        float tot = red[0] + red[1] + red[2] + red[3];
        if (threadIdx.x == 0) mag[tok] = sqrtf(tot) * 0.036084391824352f;  // 1/sqrt(768)
        bf16_t* xo = xb + (size_t)tok * 768;
        for (int c = threadIdx.x; c < 768; c += 256) xo[c] = (bf16_t)xr[c];
    }
}

// ---------------------------------------------------------------------------
// 3) GEMM1: qkv = xb(8192x768) @ wn^T(2304x768).  128x128 tile, BK=32,
//    distance-2 register prefetch with NAMED registers. Lane-order LDS.
//    Epilogue: q/k per-head normalize (q also *kC) -> qkvh; v (p==2)
//    transposed via LDS to vT (pi-permuted columns).
// ---------------------------------------------------------------------------
__global__ __launch_bounds__(256, 2) void gemm_qkv_kernel(const bf16_t* __restrict__ A,
                                                          const bf16_t* __restrict__ Bw,
                                                          bf16_t* __restrict__ qkvh,
                                                          bf16_t* __restrict__ vT) {
    __shared__ __align__(16) bf16_t sm[8704];   // As 4096 | Bs 4096; reused 64x136 for v-transpose
    bf16_t* As = sm;
    bf16_t* Bs = sm + 4096;

    const int m0 = blockIdx.x * 128;
    const int n0 = blockIdx.y * 128;
    const int tid = threadIdx.x;
    const int wave = tid >> 6, lane = tid & 63;
    const int quad = lane >> 4, l16 = lane & 15;
    const int wr = (wave >> 1) * 64, wc = (wave & 1) * 64;
    const int srow = lane & 15, schunk = lane >> 4;   // staging lane map

    floatx4 acc[4][4];
    for (int i = 0; i < 4; i++)
        for (int j = 0; j < 4; j++) acc[i][j] = (floatx4){0.f, 0.f, 0.f, 0.f};

    const bf16_t* aptr0 = A  + (size_t)(m0 + wave * 32 + srow) * 768 + schunk * 8;
    const bf16_t* bptr0 = Bw + (size_t)(n0 + wave * 32 + srow) * 768 + schunk * 8;
    const int abase = wave * 1024;                    // per-wave region: 2 x 512

    // two prefetch sets, NAMED registers (arrays spilled in R9)
    uint4 aA0, aA1, bA0, bA1, aB0, aB1, bB0, bB1;

    aA0 = *(const uint4*)(aptr0 + 0);
    aA1 = *(const uint4*)(aptr0 + 0 + 16 * 768);
    bA0 = *(const uint4*)(bptr0 + 0);
    bA1 = *(const uint4*)(bptr0 + 0 + 16 * 768);
    aB0 = *(const uint4*)(aptr0 + 32);
    aB1 = *(const uint4*)(aptr0 + 32 + 16 * 768);
    bB0 = *(const uint4*)(bptr0 + 32);
    bB1 = *(const uint4*)(bptr0 + 32 + 16 * 768);

    auto compute = [&]() {
        bf16x8 af[4], bfr[4];
#pragma unroll
        for (int i = 0; i < 4; i++)
            af[i] = *(const bf16x8*)&As[((wr >> 4) + i) * 512 + quad * 128 + l16 * 8];
#pragma unroll
        for (int j = 0; j < 4; j++)
            bfr[j] = *(const bf16x8*)&Bs[((wc >> 4) + j) * 512 + quad * 128 + l16 * 8];
#pragma unroll
        for (int i = 0; i < 4; i++)
#pragma unroll
            for (int j = 0; j < 4; j++) acc[i][j] = MFMA16x16x32(af[i], bfr[j], acc[i][j]);
    };

    for (int u = 0; u < 12; ++u) {
        // even iteration: consume set A, refill A for k=(2u+2)*32
        __syncthreads();
        *(uint4*)&As[abase + lane * 8]       = aA0;
        *(uint4*)&As[abase + 512 + lane * 8] = aA1;
        *(uint4*)&Bs[abase + lane * 8]       = bA0;
        *(uint4*)&Bs[abase + 512 + lane * 8] = bA1;
        if (u < 11) {
            int k0 = (2 * u + 2) * 32;
            aA0 = *(const uint4*)(aptr0 + k0);
            aA1 = *(const uint4*)(aptr0 + k0 + 16 * 768);
            bA0 = *(const uint4*)(bptr0 + k0);
            bA1 = *(const uint4*)(bptr0 + k0 + 16 * 768);
        }
        __syncthreads();
        compute();

        // odd iteration: consume set B, refill B for k=(2u+3)*32
        __syncthreads();
        *(uint4*)&As[abase + lane * 8]       = aB0;
        *(uint4*)&As[abase + 512 + lane * 8] = aB1;
        *(uint4*)&Bs[abase + lane * 8]       = bB0;
        *(uint4*)&Bs[abase + 512 + lane * 8] = bB1;
        if (u < 11) {
            int k0 = (2 * u + 3) * 32;
            aB0 = *(const uint4*)(aptr0 + k0);
            aB1 = *(const uint4*)(aptr0 + k0 + 16 * 768);
            bB0 = *(const uint4*)(bptr0 + k0);
            bB1 = *(const uint4*)(bptr0 + k0 + 16 * 768);
        }
        __syncthreads();
        compute();
    }

    const int p = n0 / 768;        // block-uniform (768 % 128 == 0)
    const int bat = m0 >> 11, t0 = m0 & 2047;

    if (p < 2) {
        // ---- q/k: fused per-head normalize, scatter to qkvh ----
        const int h = ((n0 + wc) - p * 768) >> 6;
        const float base = (p == 0) ? kC * 8.0f : 8.0f;
        for (int i = 0; i < 4; i++)
            for (int r = 0; r < 4; r++) {
                float vals[4], ss = 0.f;
                for (int j = 0; j < 4; j++) { float v = acc[i][j][r]; vals[j] = v; ss += v * v; }
                ss += __shfl_xor(ss, 1, 64);
                ss += __shfl_xor(ss, 2, 64);
                ss += __shfl_xor(ss, 4, 64);
                ss += __shfl_xor(ss, 8, 64);
                float scale = base / (sqrtf(ss) + kEPS);
                int m = m0 + wr + i * 16 + quad * 4 + r;
                int t = m & 2047;
                bf16_t* dst = qkvh + ((((size_t)p * 4 + bat) * 12 + h) * 2048 + t) * 64;
                for (int j = 0; j < 4; j++) dst[j * 16 + l16] = (bf16_t)(vals[j] * scale);
            }
    } else {
        // ---- v: transpose via LDS, write vT[(bh)*64+d][t] pi-permuted ----
        __syncthreads();                         // everyone done with As/Bs
        const int h0 = (n0 - 1536) >> 6;         // block head base (2 heads/block)
        for (int hh = 0; hh < 2; hh++) {
            if ((wc >> 6) == hh) {
                for (int i = 0; i < 4; i++)
                    for (int r = 0; r < 4; r++) {
                        int tl = wr + i * 16 + quad * 4 + r;
                        for (int j = 0; j < 4; j++)
                            sm[(j * 16 + l16) * 136 + tl] = (bf16_t)acc[i][j][r];
                    }
            }
            __syncthreads();
            bf16_t* dst = vT + ((size_t)(bat * 12 + h0 + hh) * 64) * 2048 + t0;
            for (int u = tid; u < 1024; u += 256) {
                int d = u >> 4, c = u & 15;
                bf16_t tmp[8];
#pragma unroll
                for (int q = 0; q < 8; q++) {
                    int sp = c * 8 + q;                      // out position 0..127
                    int q6 = sp & 63;
                    int tl = (sp & 64) + ((q6 & 3) << 4) + (q6 >> 2);   // pi_inv
                    tmp[q] = sm[d * 136 + tl];
                }
                *(uint4*)&dst[(size_t)d * 2048 + c * 8] = *(uint4*)tmp;
            }
            __syncthreads();
        }
    }
}

// ---------------------------------------------------------------------------
// attn phase macros — named accumulators, no pointer params (spill-proof).
// QK_TILE: S(cur) = Q.K^T for one 64-tile (16 q-rows x 64 s per wave).
// FINISH:  sigmoid(S(prev)) -> Ps (LDS, wave-private rows) -> O += P.V.
// ---------------------------------------------------------------------------
#define QK_TILE(S0_, S1_, S2_, S3_, KSBUF)                                        \
    do {                                                                          \
        const bf16_t* Ks_ = (KSBUF);                                              \
        __builtin_amdgcn_s_setprio(1);                                            \
        {   int row_ = 0 * 16 + l16;                                              \
            bf16x8 b0_ = *(const bf16x8*)&Ks_[row_ * 64 + ((quad ^ (l16 & 7)) * 8)];       \
            bf16x8 b1_ = *(const bf16x8*)&Ks_[row_ * 64 + (((4 + quad) ^ (l16 & 7)) * 8)]; \
            S0_ = MFMA16x16x32(qf0, b0_, fz);                                     \
            S0_ = MFMA16x16x32(qf1, b1_, S0_); }                                  \
        {   int row_ = 1 * 16 + l16;                                              \
            bf16x8 b0_ = *(const bf16x8*)&Ks_[row_ * 64 + ((quad ^ (l16 & 7)) * 8)];       \
            bf16x8 b1_ = *(const bf16x8*)&Ks_[row_ * 64 + (((4 + quad) ^ (l16 & 7)) * 8)]; \
            S1_ = MFMA16x16x32(qf0, b0_, fz);                                     \
            S1_ = MFMA16x16x32(qf1, b1_, S1_); }                                  \
        {   int row_ = 2 * 16 + l16;                                              \
            bf16x8 b0_ = *(const bf16x8*)&Ks_[row_ * 64 + ((quad ^ (l16 & 7)) * 8)];       \
            bf16x8 b1_ = *(const bf16x8*)&Ks_[row_ * 64 + (((4 + quad) ^ (l16 & 7)) * 8)]; \
            S2_ = MFMA16x16x32(qf0, b0_, fz);                                     \
            S2_ = MFMA16x16x32(qf1, b1_, S2_); }                                  \
        {   int row_ = 3 * 16 + l16;                                              \
            bf16x8 b0_ = *(const bf16x8*)&Ks_[row_ * 64 + ((quad ^ (l16 & 7)) * 8)];       \
            bf16x8 b1_ = *(const bf16x8*)&Ks_[row_ * 64 + (((4 + quad) ^ (l16 & 7)) * 8)]; \
            S3_ = MFMA16x16x32(qf0, b0_, fz);                                     \
            S3_ = MFMA16x16x32(qf1, b1_, S3_); }                                  \
        __builtin_amdgcn_s_setprio(0);                                            \
    } while (0)

#define FINISH(S0_, S1_, S2_, S3_, VTBUF)                                         \
    do {                                                                          \
        const bf16_t* Vt_ = (VTBUF);                                              \
        _Pragma("unroll")                                                         \
        for (int r_ = 0; r_ < 4; r_++) {                                          \
            int row_ = wave * 16 + quad * 4 + r_;                                 \
            float t0_ = __builtin_amdgcn_rcpf(1.0f + __builtin_amdgcn_exp2f(S0_[r_])); \
            float t1_ = __builtin_amdgcn_rcpf(1.0f + __builtin_amdgcn_exp2f(S1_[r_])); \
            float t2_ = __builtin_amdgcn_rcpf(1.0f + __builtin_amdgcn_exp2f(S2_[r_])); \
            float t3_ = __builtin_amdgcn_rcpf(1.0f + __builtin_amdgcn_exp2f(S3_[r_])); \
            bf16x2 lo_ = pk_bf16(t0_, t1_);                                       \
            bf16x2 hi_ = pk_bf16(t2_, t3_);                                       \
            bf16x4 pk_ = __builtin_shufflevector(lo_, hi_, 0, 1, 2, 3);           \
            *(bf16x4*)&QP[row_ * 64 + (((l16 >> 1) ^ (row_ & 7)) * 8) + (l16 & 1) * 4] = pk_; \
        }                                                                         \
        const int prow_ = wave * 16 + l16;                                        \
        bf16x8 af0_ = *(const bf16x8*)&QP[prow_ * 64 + ((quad ^ (l16 & 7)) * 8)];       \
        bf16x8 af1_ = *(const bf16x8*)&QP[prow_ * 64 + (((4 + quad) ^ (l16 & 7)) * 8)]; \
        __builtin_amdgcn_s_setprio(1);                                            \
        _Pragma("unroll")                                                         \
        for (int j_ = 0; j_ < 4; j_++) {                                          \
            int row_ = j_ * 16 + l16;                                             \
            bf16x8 b0_ = *(const bf16x8*)&Vt_[row_ * 64 + ((quad ^ (l16 & 7)) * 8)];       \
            bf16x8 b1_ = *(const bf16x8*)&Vt_[row_ * 64 + (((4 + quad) ^ (l16 & 7)) * 8)]; \
            o[j_] = MFMA16x16x32(af0_, b0_, o[j_]);                               \
            o[j_] = MFMA16x16x32(af1_, b1_, o[j_]);                               \
        }                                                                         \
        __builtin_amdgcn_s_setprio(0);                                            \
    } while (0)

// ---------------------------------------------------------------------------
// 6) sigmoid attention, fused per-head output normalize + mag rescale.
//    grid (48, 16): x = head (XCD-affine), y = q-tile. 512 thr = 8 waves x
//    16 q-rows. s-tile 64, one barrier per s-tile.
//    R13 pipeline: iter i reads K(i) [Ksh[i&1]] and V(i-1) [Vsh[(i-1)&1]];
//    writes K(i+1) [Ksh[(i+1)&1]] and V(i) [Vsh[i&1]]. Even tiles -> sA,
//    odd tiles -> sB.
// ---------------------------------------------------------------------------
__global__ __launch_bounds__(512, 4) void attn_kernel(const bf16_t* __restrict__ qkvh,
                                                      const bf16_t* __restrict__ vT,
                                                      const float* __restrict__ mag,
                                                      bf16_t* __restrict__ y) {
    __shared__ bf16_t QP[128 * 64];          // Q tile, then reused as Ps (wave-private rows)
    __shared__ bf16_t Ksh[2][64 * 64];
    __shared__ bf16_t Vsh[2][64 * 64];       // pi-ordered V

    const int bh = blockIdx.x, bat = bh / 12, h = bh % 12;
    const int m0 = blockIdx.y * 128;
    const bf16_t* qbase = qkvh + (((size_t)bat * 12 + h) * 2048) * 64;            // p=0
    const bf16_t* kbase = qkvh + (((size_t)(4 + bat) * 12 + h) * 2048) * 64;      // p=1
    const bf16_t* vbase = vT + ((size_t)bh * 64) * 2048;

    const int tid = threadIdx.x, wave = tid >> 6, lane = tid & 63;
    const int quad = lane >> 4, l16 = lane & 15;

    // ---- stage Q (swizzled): 1024 uint4 over 512 threads ----
    for (int s = tid; s < 1024; s += 512) {
        int r = s >> 3, blk = s & 7;
        *(uint4*)&QP[r * 64 + ((blk ^ (r & 7)) * 8)] =
            *(const uint4*)&qbase[(size_t)(m0 + r) * 64 + blk * 8];
    }

    // ---- K/V prefetch (1 uint4 of each per thread, independent schedules) ----
    uint4 kr, vr;
    const int slr = tid >> 3, slb = tid & 7;
    const int sw = ((slb ^ (slr & 7)) * 8);
    auto issueK  = [&](int s0) { kr = *(const uint4*)&kbase[(size_t)(s0 + slr) * 64 + slb * 8]; };
    auto issueV  = [&](int s0) { vr = *(const uint4*)&vbase[(size_t)slr * 2048 + s0 + slb * 8]; };
    auto commitK = [&](int buf) { *(uint4*)&Ksh[buf][slr * 64 + sw] = kr; };
    auto commitV = [&](int buf) { *(uint4*)&Vsh[buf][slr * 64 + sw] = vr; };

    issueK(0);
    __syncthreads();   // Q staged

    // ---- Q fragments -> registers (wave-private rows; QP freed for Ps) ----
    const int qrow = wave * 16 + l16;
    bf16x8 qf0 = *(const bf16x8*)&QP[qrow * 64 + ((quad ^ (l16 & 7)) * 8)];
    bf16x8 qf1 = *(const bf16x8*)&QP[qrow * 64 + (((4 + quad) ^ (l16 & 7)) * 8)];

    commitK(0);        // K(0)
    issueK(64);        // K(1)
    issueV(0);         // V(0)
    __syncthreads();   // Ksh[0] visible; all qf reads done before Ps writes

    const floatx4 fz = (floatx4){0.f, 0.f, 0.f, 0.f};   // loop-invariant zero C

    floatx4 o[4];
#pragma unroll
    for (int j = 0; j < 4; j++) o[j] = fz;

    floatx4 sA0, sA1, sA2, sA3;   // even-tile S
    floatx4 sB0, sB1, sB2, sB3;   // odd-tile S

    // ---- pipeline prologue: compute S(0); commit K(1), V(0); load K(2), V(1)
    QK_TILE(sA0, sA1, sA2, sA3, Ksh[0]);
    commitK(1);
    commitV(0);
    issueK(128);
    issueV(64);
    __syncthreads();   // K(1), V(0) visible

    // ---- steady state: pairs (1,2)..(29,30). Invariant at top of iter i:
    //      K(i),V(i-1) visible; kr=K(i+1), vr=V(i); prev S(i-1) resident.
    for (int i = 1; i < 31; i += 2) {
        // iter i (odd): cur=sB, prev=sA
        QK_TILE(sB0, sB1, sB2, sB3, Ksh[1]);   // K(i) lives in Ksh[1]
        commitK(0);                            // K(i+1) -> Ksh[0]
        commitV(1);                            // V(i)   -> Vsh[1]
        issueK((i + 2) * 64);                  // K(i+2)  (i<=29 -> tile <=31, valid)
        issueV((i + 1) * 64);                  // V(i+1)
        FINISH(sA0, sA1, sA2, sA3, Vsh[0]);    // sigmoid S(i-1), PV with V(i-1)
        __syncthreads();

        // iter i+1 (even): cur=sA, prev=sB
        QK_TILE(sA0, sA1, sA2, sA3, Ksh[0]);
        commitK(1);                            // K(i+2) -> Ksh[1]  (i+2 <= 31, valid)
        commitV(0);                            // V(i+1) -> Vsh[0]
        if (i < 29) issueK((i + 3) * 64);
        issueV((i + 2) * 64);                  // V(i+2)  (i+2 <= 31, valid)
        FINISH(sB0, sB1, sB2, sB3, Vsh[1]);
        __syncthreads();
    }

    // ---- iter 31: last QK; commit V(31); finish S(30)
    QK_TILE(sB0, sB1, sB2, sB3, Ksh[1]);       // K(31) in Ksh[1]
    commitV(1);                                // V(31) -> Vsh[1]
    FINISH(sA0, sA1, sA2, sA3, Vsh[0]);        // S(30) with V(30)
    __syncthreads();                           // V(31) visible

    // ---- drain: finish S(31)
    FINISH(sB0, sB1, sB2, sB3, Vsh[1]);

    // ---- epilogue: out = mag * 8 * (kGAIN/sqrt(T)) * o / (||...|| + eps) ----
    const float kfac = kGAIN * 0.02209708691207961f;  // 1.8402/sqrt(2048)
#pragma unroll
    for (int r = 0; r < 4; r++) {
        int t = m0 + wave * 16 + quad * 4 + r;
        float vals[4];
        float ss = 0.f;
#pragma unroll
        for (int j = 0; j < 4; j++) {
            float v = o[j][r] * kfac;
            vals[j] = v;
            ss += v * v;
        }
        for (int msk = 1; msk < 16; msk <<= 1) ss += __shfl_xor(ss, msk, 64);
        float mg = mag[bat * 2048 + t];
        float sc = mg * 8.0f / (sqrtf(ss) + kEPS);
#pragma unroll
        for (int j = 0; j < 4; j++) {
            int d = j * 16 + l16;
            y[((size_t)(bat * 2048 + t)) * 768 + h * 64 + d] = (bf16_t)(vals[j] * sc);
        }
    }
}

// ---------------------------------------------------------------------------
// 7) GEMM2: out = y(8192x768) @ ow^T(768x768) -> fp32, BK=32, distance-2
//    (named prefetch registers, launch_bounds(256,2))
// ---------------------------------------------------------------------------
__global__ __launch_bounds__(256, 2) void gemm_out_kernel(const bf16_t* __restrict__ A,
                                                          const bf16_t* __restrict__ Bw,
                                                          float* __restrict__ out) {
    __shared__ __align__(16) bf16_t sm[8192];
    bf16_t* As = sm;
    bf16_t* Bs = sm + 4096;

    const int m0 = blockIdx.x * 128;
    const int n0 = blockIdx.y * 128;
    const int tid = threadIdx.x;
    const int wave = tid >> 6, lane = tid & 63;
    const int quad = lane >> 4, l16 = lane & 15;
    const int wr = (wave >> 1) * 64, wc = (wave & 1) * 64;
    const int srow = lane & 15, schunk = lane >> 4;

    floatx4 acc[4][4];
    for (int i = 0; i < 4; i++)
        for (int j = 0; j < 4; j++) acc[i][j] = (floatx4){0.f, 0.f, 0.f, 0.f};

    const bf16_t* aptr0 = A  + (size_t)(m0 + wave * 32 + srow) * 768 + schunk * 8;
    const bf16_t* bptr0 = Bw + (size_t)(n0 + wave * 32 + srow) * 768 + schunk * 8;
    const int abase = wave * 1024;

    uint4 aA0, aA1, bA0, bA1, aB0, aB1, bB0, bB1;

    aA0 = *(const uint4*)(aptr0 + 0);
    aA1 = *(const uint4*)(aptr0 + 0 + 16 * 768);
    bA0 = *(const uint4*)(bptr0 + 0);
    bA1 = *(const uint4*)(bptr0 + 0 + 16 * 768);
    aB0 = *(const uint4*)(aptr0 + 32);
    aB1 = *(const uint4*)(aptr0 + 32 + 16 * 768);
    bB0 = *(const uint4*)(bptr0 + 32);
    bB1 = *(const uint4*)(bptr0 + 32 + 16 * 768);

    auto compute = [&]() {
        bf16x8 af[4], bfr[4];
#pragma unroll
        for (int i = 0; i < 4; i++)
            af[i] = *(const bf16x8*)&As[((wr >> 4) + i) * 512 + quad * 128 + l16 * 8];
#pragma unroll
        for (int j = 0; j < 4; j++)
            bfr[j] = *(const bf16x8*)&Bs[((wc >> 4) + j) * 512 + quad * 128 + l16 * 8];
#pragma unroll
        for (int i = 0; i < 4; i++)
#pragma unroll
            for (int j = 0; j < 4; j++) acc[i][j] = MFMA16x16x32(af[i], bfr[j], acc[i][j]);
    };

    for (int u = 0; u < 12; ++u) {
        __syncthreads();
        *(uint4*)&As[abase + lane * 8]       = aA0;
        *(uint4*)&As[abase + 512 + lane * 8] = aA1;
        *(uint4*)&Bs[abase + lane * 8]       = bA0;
        *(uint4*)&Bs[abase + 512 + lane * 8] = bA1;
        if (u < 11) {
            int k0 = (2 * u + 2) * 32;
            aA0 = *(const uint4*)(aptr0 + k0);
            aA1 = *(const uint4*)(aptr0 + k0 + 16 * 768);
            bA0 = *(const uint4*)(bptr0 + k0);
            bA1 = *(const uint4*)(bptr0 + k0 + 16 * 768);
        }
        __syncthreads();
        compute();

        __syncthreads();
        *(uint4*)&As[abase + lane * 8]       = aB0;
        *(uint4*)&As[abase + 512 + lane * 8] = aB1;
        *(uint4*)&Bs[abase + lane * 8]       = bB0;
        *(uint4*)&Bs[abase + 512 + lane * 8] = bB1;
        if (u < 11) {
            int k0 = (2 * u + 3) * 32;
            aB0 = *(const uint4*)(aptr0 + k0);
            aB1 = *(const uint4*)(aptr0 + k0 + 16 * 768);
            bB0 = *(const uint4*)(bptr0 + k0);
            bB1 = *(const uint4*)(bptr0 + k0 + 16 * 768);
        }
        __syncthreads();
        compute();
    }

    for (int i = 0; i < 4; i++)
        for (int j = 0; j < 4; j++) {
            int n = n0 + wc + j * 16 + l16;
            for (int r = 0; r < 4; r++) {
                int m = m0 + wr + i * 16 + quad * 4 + r;
                out[(size_t)m * 768 + n] = acc[i][j][r];
            }
        }
}

// ---------------------------------------------------------------------------
extern "C" void kernel_launch(void* const* d_in, const int* in_sizes, int n_in,
                              void* d_out, int out_size, void* d_ws, size_t ws_size,
                              hipStream_t stream) {
    const float* x     = (const float*)d_in[0];   // (4,2048,768)
    const float* qkv_w = (const float*)d_in[1];   // (2304,768)
    const float* out_w = (const float*)d_in[2];   // (768,768)
    float* out = (float*)d_out;

    char* ws = (char*)d_ws;
    bf16_t* wn_all = (bf16_t*)(ws + 0);          //  4,718,592  (3072x768 bf16: qkv_w rows then out_w rows)
    bf16_t* xb     = (bf16_t*)(ws + 4718592);    // 12,582,912  (8192x768 bf16)
    float*  mag    = (float*) (ws + 17301504);   //     32,768  (8192 fp32)
    bf16_t* qkvh   = (bf16_t*)(ws + 17334272);   // 25,165,824  (2x4x12x2048x64 bf16: q,k)
    bf16_t* vT     = (bf16_t*)(ws + 42500096);   // 12,582,912  (48x64x2048 bf16, pi-permuted cols)
    bf16_t* y      = (bf16_t*)(ws + 55083008);   // 12,582,912  (8192x768 bf16)
    // total 67,665,920 bytes

    bf16_t* ow = wn_all + (size_t)2304 * 768;

    prep_kernel<<<11264, 256, 0, stream>>>(x, qkv_w, out_w, wn_all, xb, mag);
    gemm_qkv_kernel<<<dim3(64, 18), 256, 0, stream>>>(xb, wn_all, qkvh, vT);
    attn_kernel<<<dim3(48, 16), 512, 0, stream>>>(qkvh, vT, mag, y);
    gemm_out_kernel<<<dim3(64, 6), 256, 0, stream>>>(y, ow, out);
}